// Round 6
// baseline (347.740 us; speedup 1.0000x reference)
//
#include <hip/hip_runtime.h>
#include <hip/hip_bf16.h>

#define NOPT    5
#define NBATCH  100000
#define MTOT    (NOPT * NBATCH)   // 500000 rows
#define KDIM    600
#define NKS     19                // k-steps of 32 (last overlaps: k=568..599)
#define NT      5                 // n-tiles of 16 (75 -> 80, tail zero-padded)
#define NBUF    4                 // per-wave rotating A buffers (depth-2 prefetch)

typedef __bf16 bf16x8 __attribute__((ext_vector_type(8)));
typedef float  f32x4  __attribute__((ext_vector_type(4)));

__device__ __forceinline__ int kstart(int s) { return (s < 18) ? (s << 5) : 568; }

// Pre-transform W1 [75][600] fp32 -> bf16 image in exact MFMA B-fragment order:
// img[(s*5+t)*512 + l*8 + j] = W1[n=t*16+(l&15)][k=kstart(s)+(l>>4)*8+j], zeros for
// n>=75 and for the duplicated k range of the overlapping tail tile (s==18, kg==0).
__global__ void prep_w1(const float* __restrict__ W1, __bf16* __restrict__ img) {
    const int s  = blockIdx.x / NT;
    const int t  = blockIdx.x % NT;
    const int l  = threadIdx.x;            // 0..63
    const int kg = l >> 4;
    const int n  = t * 16 + (l & 15);
    const int ks = kstart(s);
    bf16x8 v;
#pragma unroll
    for (int j = 0; j < 8; ++j) {
        const int k = ks + kg * 8 + j;
        float f = 0.0f;
        if (n < 75 && !(s == 18 && kg == 0)) f = W1[n * KDIM + k];
        v[j] = (__bf16)f;
    }
    *(bf16x8*)(img + ((size_t)blockIdx.x * 64 + l) * 8) = v;
}

// Wave-private barrier-free pipeline with EXPLICIT counted vmcnt waits.
// Issue order is pinned by sched_barrier(0) fences + #pragma unroll 1 so the
// per-iteration vmem pattern is exactly [A-DMA x2][B-load x5]; vmcnt(14)
// before compute(s) forces A(s) (and all older ops) to have landed while
// leaving the 14 younger prefetch ops in flight. No __syncthreads anywhere.
__global__ void __launch_bounds__(256, 4) ans_sel_kernel(
    const float* __restrict__ A,     // [500000][600] fp32
    const float* __restrict__ b1,    // [75]
    const float* __restrict__ W2,    // [75]
    const float* __restrict__ b2,    // [1]
    const __bf16* __restrict__ img,  // prepped W1 fragments
    float* __restrict__ out)         // [100000][5]
{
    __shared__ f32x4 As[4][NBUF][128];  // [wave][buf][16 rows x 8 chunks] = 32 KB

    const int tid  = threadIdx.x;
    const int w    = tid >> 6;       // wave 0..3
    const int l    = tid & 63;
    const int kg   = l >> 4;
    const int ln16 = l & 15;
    const int row0 = blockIdx.x * 64;

    // A DMA geometry (proven R1 shape): lane l sources global chunk (pch^lr8)
    // of row lr8 (+8 for DMA #2); LDS dest is linear lane*16B (rule #21:
    // swizzle the SOURCE, keep dest linear). LDS slot [r*8+p] = chunk (p^r).
    const int lr8 = l >> 3;          // 0..7
    const int pch = l & 7;
    int g0 = row0 + w * 16 + lr8;     if (g0 >= MTOT) g0 = MTOT - 1;
    int g1 = row0 + w * 16 + lr8 + 8; if (g1 >= MTOT) g1 = MTOT - 1;
    const float* ap0 = A + (size_t)g0 * KDIM + (pch ^ lr8) * 4;
    const float* ap1 = A + (size_t)g1 * KDIM + (pch ^ lr8) * 4;

    auto stageA = [&](int buf, int s) {
        const int k0 = kstart(s);
        __builtin_amdgcn_global_load_lds(
            (const __attribute__((address_space(1))) void*)(ap0 + k0),
            (__attribute__((address_space(3))) void*)(&As[w][buf][0]),
            16, 0, 0);
        __builtin_amdgcn_global_load_lds(
            (const __attribute__((address_space(1))) void*)(ap1 + k0),
            (__attribute__((address_space(3))) void*)(&As[w][buf][64]),
            16, 0, 0);
    };

    const __bf16* bp = img + (size_t)l * 8;
    auto LDB = [&](int s, bf16x8& v0, bf16x8& v1, bf16x8& v2, bf16x8& v3, bf16x8& v4) {
        const __bf16* p = bp + (size_t)s * (NT * 512);
        v0 = *(const bf16x8*)(p);
        v1 = *(const bf16x8*)(p + 512);
        v2 = *(const bf16x8*)(p + 1024);
        v3 = *(const bf16x8*)(p + 1536);
        v4 = *(const bf16x8*)(p + 2048);
    };

    f32x4 acc[NT];
#pragma unroll
    for (int t = 0; t < NT; ++t) acc[t] = (f32x4){0.f, 0.f, 0.f, 0.f};

    auto compute = [&](int buf, bf16x8 v0, bf16x8 v1, bf16x8 v2, bf16x8 v3, bf16x8 v4) {
        const f32x4* base = &As[w][buf][ln16 * 8];
        const int x = ln16 & 7;
        f32x4 fa0 = base[(kg * 2)     ^ x];   // slot c^x holds global chunk c
        f32x4 fa1 = base[(kg * 2 + 1) ^ x];
        bf16x8 a;
        a[0] = (__bf16)fa0[0]; a[1] = (__bf16)fa0[1];
        a[2] = (__bf16)fa0[2]; a[3] = (__bf16)fa0[3];
        a[4] = (__bf16)fa1[0]; a[5] = (__bf16)fa1[1];
        a[6] = (__bf16)fa1[2]; a[7] = (__bf16)fa1[3];
        acc[0] = __builtin_amdgcn_mfma_f32_16x16x32_bf16(a, v0, acc[0], 0, 0, 0);
        acc[1] = __builtin_amdgcn_mfma_f32_16x16x32_bf16(a, v1, acc[1], 0, 0, 0);
        acc[2] = __builtin_amdgcn_mfma_f32_16x16x32_bf16(a, v2, acc[2], 0, 0, 0);
        acc[3] = __builtin_amdgcn_mfma_f32_16x16x32_bf16(a, v3, acc[3], 0, 0, 0);
        acc[4] = __builtin_amdgcn_mfma_f32_16x16x32_bf16(a, v4, acc[4], 0, 0, 0);
    };

    bf16x8 cb0, cb1, cb2, cb3, cb4, nb0, nb1, nb2, nb3, nb4;

    // Prologue: A(0), A(1) DMAs in flight; B(0) in regs.
    stageA(0, 0);
    stageA(1, 1);
    LDB(0, cb0, cb1, cb2, cb3, cb4);
    __builtin_amdgcn_sched_barrier(0);

    // Steady state, issue order pinned: [A(s+2) x2][B(s+1) x5][wait][compute(s)].
    // Ops younger than A(s): A(s+1)2 + B(s)5 + A(s+2)2 + B(s+1)5 = 14.
#pragma unroll 1
    for (int s = 0; s < NKS - 2; ++s) {       // s = 0..16
        stageA((s + 2) & 3, s + 2);
        __builtin_amdgcn_sched_barrier(0);
        LDB(s + 1, nb0, nb1, nb2, nb3, nb4);
        __builtin_amdgcn_sched_barrier(0);
        asm volatile("s_waitcnt vmcnt(14)" ::: "memory");
        __builtin_amdgcn_sched_barrier(0);
        compute(s & 3, cb0, cb1, cb2, cb3, cb4);
        cb0 = nb0; cb1 = nb1; cb2 = nb2; cb3 = nb3; cb4 = nb4;
    }
    // s = 17: no A(19). Younger than A(17) in flight at most: A(18)2+B(17)5+B(18)5.
    LDB(NKS - 1, nb0, nb1, nb2, nb3, nb4);
    __builtin_amdgcn_sched_barrier(0);
    asm volatile("s_waitcnt vmcnt(12)" ::: "memory");
    __builtin_amdgcn_sched_barrier(0);
    compute((NKS - 2) & 3, cb0, cb1, cb2, cb3, cb4);
    cb0 = nb0; cb1 = nb1; cb2 = nb2; cb3 = nb3; cb4 = nb4;
    // s = 18: allow only the 5 B(18) loads to remain outstanding -> A(18) landed.
    asm volatile("s_waitcnt vmcnt(5)" ::: "memory");
    __builtin_amdgcn_sched_barrier(0);
    compute((NKS - 1) & 3, cb0, cb1, cb2, cb3, cb4);

    // Epilogue: C[row=(kg*4+q)][n=t*16+ln16] per lane (verified m89/m91 layout).
    float sq[4] = {0.f, 0.f, 0.f, 0.f};
#pragma unroll
    for (int t = 0; t < NT; ++t) {
        const int n = t * 16 + ln16;
        const float b1v = (n < 75) ? b1[n] : 0.f;
        const float w2v = (n < 75) ? W2[n] : 0.f;
#pragma unroll
        for (int q = 0; q < 4; ++q) {
            float h = acc[t][q] + b1v;
            h = h > 0.f ? h : 0.f;
            sq[q] += h * w2v;
        }
    }
#pragma unroll
    for (int m = 1; m < 16; m <<= 1) {
#pragma unroll
        for (int q = 0; q < 4; ++q) sq[q] += __shfl_xor(sq[q], m, 64);
    }
    if (ln16 == 0) {
        const float bb = b2[0];
#pragma unroll
        for (int q = 0; q < 4; ++q) {
            const int R = row0 + w * 16 + kg * 4 + q;   // global row = o*NBATCH + b
            if (R < MTOT) {
                const int o = R / NBATCH;
                const int b = R % NBATCH;
                out[(size_t)b * NOPT + o] = sq[q] + bb;
            }
        }
    }
}

extern "C" void kernel_launch(void* const* d_in, const int* in_sizes, int n_in,
                              void* d_out, int out_size, void* d_ws, size_t ws_size,
                              hipStream_t stream) {
    const float* A  = (const float*)d_in[0];
    const float* W1 = (const float*)d_in[1];
    const float* b1 = (const float*)d_in[2];
    const float* W2 = (const float*)d_in[3];
    const float* b2 = (const float*)d_in[4];
    float* out = (float*)d_out;
    __bf16* img = (__bf16*)d_ws;     // needs 19*5*64*8*2 = 97280 B

    prep_w1<<<NKS * NT, 64, 0, stream>>>(W1, img);

    const int grid = (MTOT + 63) / 64;   // 7813 blocks, 4 independent waves each
    ans_sel_kernel<<<grid, 256, 0, stream>>>(A, b1, W2, b2, img, out);
}

// Round 7
// 272.621 us; speedup vs baseline: 1.2755x; 1.2755x over previous
//
#include <hip/hip_runtime.h>
#include <hip/hip_bf16.h>

#define NOPT    5
#define NBATCH  100000
#define MTOT    (NOPT * NBATCH)   // 500000 rows
#define KDIM    600
#define NKS     19                // k-steps of 32 (last overlaps: k=568..599)
#define NT      5                 // n-tiles of 16 (75 -> 80, tail zero-padded)
#define NBUF    4                 // rotating stage buffers (depth-2 prefetch)

typedef __bf16 bf16x8 __attribute__((ext_vector_type(8)));
typedef float  f32x4  __attribute__((ext_vector_type(4)));

__device__ __forceinline__ int kstart(int s) { return (s < 18) ? (s << 5) : 568; }

// Pre-transform W1 [75][600] fp32 -> bf16 image in exact MFMA B-fragment order:
// img[(s*5+t)*512 + l*8 + j] = W1[n=t*16+(l&15)][k=kstart(s)+(l>>4)*8+j], zeros for
// n>=75 and for the duplicated k range of the overlapping tail tile (s==18, kg==0).
__global__ void prep_w1(const float* __restrict__ W1, __bf16* __restrict__ img) {
    const int s  = blockIdx.x / NT;
    const int t  = blockIdx.x % NT;
    const int l  = threadIdx.x;            // 0..63
    const int kg = l >> 4;
    const int n  = t * 16 + (l & 15);
    const int ks = kstart(s);
    bf16x8 v;
#pragma unroll
    for (int j = 0; j < 8; ++j) {
        const int k = ks + kg * 8 + j;
        float f = 0.0f;
        if (n < 75 && !(s == 18 && kg == 0)) f = W1[n * KDIM + k];
        v[j] = (__bf16)f;
    }
    *(bf16x8*)(img + ((size_t)blockIdx.x * 64 + l) * 8) = v;
}

// R1 staging shape (all global_load_lds, consumption via ds_read only -> B is
// lgkm-decoupled from vmcnt) + T3/T4: raw s_barrier with counted vmcnt, never
// a drain. Issue order pinned by sched_barrier(0) + unroll 1; per-wave stage =
// 2 A-DMA + 1-2 B-DMA, so vmcnt(6) (<= 2 stages in flight) proves stage(s)
// landed for every wave. Depth-2 prefetch across 4 rotating buffers; buffer
// reuse is separated by a full barrier generation (WAR-safe), each LDS slot
// has a single writer wave (WAW-safe via its own vmcnt).
__global__ void __launch_bounds__(256, 3) ans_sel_kernel(
    const float* __restrict__ A,     // [500000][600] fp32
    const float* __restrict__ b1,    // [75]
    const float* __restrict__ W2,    // [75]
    const float* __restrict__ b2,    // [1]
    const __bf16* __restrict__ img,  // prepped W1 fragments
    float* __restrict__ out)         // [100000][5]
{
    __shared__ f32x4  As[NBUF][4][128];  // [buf][wave][16 rows x 8 chunks] = 32 KB
    __shared__ __bf16 Bs[NBUF][2560];    // [buf][5 parts x 512] = 20 KB

    const int tid  = threadIdx.x;
    const int w    = tid >> 6;       // wave 0..3
    const int l    = tid & 63;
    const int kg   = l >> 4;
    const int ln16 = l & 15;
    const int row0 = blockIdx.x * 64;

    // A DMA geometry (proven R1 shape): lane l sources global chunk (pch^lr8)
    // of row lr8 (+8 for DMA #2); LDS dest linear lane*16B (rule #21: swizzle
    // the SOURCE, dest stays linear). LDS slot [r*8+p] holds chunk (p^r).
    const int lr8 = l >> 3;          // 0..7
    const int pch = l & 7;
    int g0 = row0 + w * 16 + lr8;     if (g0 >= MTOT) g0 = MTOT - 1;
    int g1 = row0 + w * 16 + lr8 + 8; if (g1 >= MTOT) g1 = MTOT - 1;
    const float* ap0 = A + (size_t)g0 * KDIM + (pch ^ lr8) * 4;
    const float* ap1 = A + (size_t)g1 * KDIM + (pch ^ lr8) * 4;

    // stage(s): wave w issues 2 A-DMAs + B parts {w, w+4<5}. All dests are
    // wave-uniform base + lane*16B.
    auto stage = [&](int buf, int s) {
        const int k0 = kstart(s);
        __builtin_amdgcn_global_load_lds(
            (const __attribute__((address_space(1))) void*)(ap0 + k0),
            (__attribute__((address_space(3))) void*)(&As[buf][w][0]),
            16, 0, 0);
        __builtin_amdgcn_global_load_lds(
            (const __attribute__((address_space(1))) void*)(ap1 + k0),
            (__attribute__((address_space(3))) void*)(&As[buf][w][64]),
            16, 0, 0);
        for (int i = w; i < NT; i += 4) {
            __builtin_amdgcn_global_load_lds(
                (const __attribute__((address_space(1))) void*)(img + (size_t)s * 2560 + i * 512 + l * 8),
                (__attribute__((address_space(3))) void*)(&Bs[buf][i * 512]),
                16, 0, 0);
        }
    };

    f32x4 acc[NT];
#pragma unroll
    for (int t = 0; t < NT; ++t) acc[t] = (f32x4){0.f, 0.f, 0.f, 0.f};

    auto compute = [&](int buf) {
        const f32x4* base = &As[buf][w][ln16 * 8];
        const int x = ln16 & 7;
        f32x4 fa0 = base[(kg * 2)     ^ x];   // slot c^x holds global chunk c
        f32x4 fa1 = base[(kg * 2 + 1) ^ x];
        bf16x8 a;
        a[0] = (__bf16)fa0[0]; a[1] = (__bf16)fa0[1];
        a[2] = (__bf16)fa0[2]; a[3] = (__bf16)fa0[3];
        a[4] = (__bf16)fa1[0]; a[5] = (__bf16)fa1[1];
        a[6] = (__bf16)fa1[2]; a[7] = (__bf16)fa1[3];
#pragma unroll
        for (int t = 0; t < NT; ++t) {
            bf16x8 b = *(const bf16x8*)(&Bs[buf][t * 512 + l * 8]);
            acc[t] = __builtin_amdgcn_mfma_f32_16x16x32_bf16(a, b, acc[t], 0, 0, 0);
        }
    };

    // Prologue: stage(0)->buf0, stage(1)->buf1 in flight.
    stage(0, 0);
    stage(1, 1);
    __builtin_amdgcn_sched_barrier(0);

    // Steady state: [stage(s+2)] [vmcnt(6)] [s_barrier] [compute(s)].
    // Per-wave ops/stage m = 3 or 4; vmcnt(6) <= 2m keeps stages s+1, s+2 in
    // flight while proving stage(s) (own ops) landed; barrier then proves ALL
    // waves' stage(s) landed.
#pragma unroll 1
    for (int s = 0; s < NKS - 2; ++s) {       // s = 0..16
        stage((s + 2) & 3, s + 2);
        __builtin_amdgcn_sched_barrier(0);
        asm volatile("s_waitcnt vmcnt(6)" ::: "memory");
        __builtin_amdgcn_sched_barrier(0);
        __builtin_amdgcn_s_barrier();
        __builtin_amdgcn_sched_barrier(0);
        compute(s & 3);
    }
    // s = 17: stages 17,18 outstanding (<= 2m ops); vmcnt(3) proves 17 landed.
    asm volatile("s_waitcnt vmcnt(3)" ::: "memory");
    __builtin_amdgcn_sched_barrier(0);
    __builtin_amdgcn_s_barrier();
    __builtin_amdgcn_sched_barrier(0);
    compute((NKS - 2) & 3);
    // s = 18: drain the last stage.
    asm volatile("s_waitcnt vmcnt(0)" ::: "memory");
    __builtin_amdgcn_sched_barrier(0);
    __builtin_amdgcn_s_barrier();
    __builtin_amdgcn_sched_barrier(0);
    compute((NKS - 1) & 3);

    // Epilogue: C[row=(kg*4+q)][n=t*16+ln16] per lane (verified m89/m91 layout).
    float sq[4] = {0.f, 0.f, 0.f, 0.f};
#pragma unroll
    for (int t = 0; t < NT; ++t) {
        const int n = t * 16 + ln16;
        const float b1v = (n < 75) ? b1[n] : 0.f;
        const float w2v = (n < 75) ? W2[n] : 0.f;
#pragma unroll
        for (int q = 0; q < 4; ++q) {
            float h = acc[t][q] + b1v;
            h = h > 0.f ? h : 0.f;
            sq[q] += h * w2v;
        }
    }
#pragma unroll
    for (int m = 1; m < 16; m <<= 1) {
#pragma unroll
        for (int q = 0; q < 4; ++q) sq[q] += __shfl_xor(sq[q], m, 64);
    }
    if (ln16 == 0) {
        const float bb = b2[0];
#pragma unroll
        for (int q = 0; q < 4; ++q) {
            const int R = row0 + w * 16 + kg * 4 + q;   // global row = o*NBATCH + b
            if (R < MTOT) {
                const int o = R / NBATCH;
                const int b = R % NBATCH;
                out[(size_t)b * NOPT + o] = sq[q] + bb;
            }
        }
    }
}

extern "C" void kernel_launch(void* const* d_in, const int* in_sizes, int n_in,
                              void* d_out, int out_size, void* d_ws, size_t ws_size,
                              hipStream_t stream) {
    const float* A  = (const float*)d_in[0];
    const float* W1 = (const float*)d_in[1];
    const float* b1 = (const float*)d_in[2];
    const float* W2 = (const float*)d_in[3];
    const float* b2 = (const float*)d_in[4];
    float* out = (float*)d_out;
    __bf16* img = (__bf16*)d_ws;     // needs 19*5*64*8*2 = 97280 B

    prep_w1<<<NKS * NT, 64, 0, stream>>>(W1, img);

    const int grid = (MTOT + 63) / 64;   // 7813 blocks, 4 waves each
    ans_sel_kernel<<<grid, 256, 0, stream>>>(A, b1, W2, b2, img, out);
}